// Round 10
// baseline (858.779 us; speedup 1.0000x reference)
//
#include <hip/hip_runtime.h>
#include <cstdint>
#include <cstddef>

// GGNN on MI355X. Round 10: r9 numerics (2-limb f16, 3 products, l1 scaled 2^11)
// with (1) 32x32x16 f16 MFMA (4060 vs 3378 FLOP/cyc) and (2) GRU fusion:
//   z-pre = W3.av + u3.h (one acc), hv-pre = W5.av, r-path = W4.av + u3.h with
//   ew1 fused in epilogue -> rh2. ew1 kernel, u3f buffer, pre r-slice deleted.
// Layouts:
//   A2f [2048: Ain|Aout][ l0(1024) | l1'(1024) ]
//   hN2f[b*128+d][ l0 | l1' ]  (rh2 overlay)
//   X2  [n*32+b][ l0: m_in(128) m_out(128) h(128) | l1' same ]  (LDX 768)
//   Wsm [384: w3|w4|w5][ l0(256)|l1'(256) ]; u3wb/u5wb [128][ l0|l1' (128) ]
//   pre [32768][256]: z-pre(128) | hv-pre(128)   (fp32, no biases)

typedef _Float16 f16;
typedef __attribute__((ext_vector_type(8))) _Float16 f16x8;
typedef __attribute__((ext_vector_type(16))) float f32x16;
typedef __attribute__((ext_vector_type(4))) float f32x4;

#define LDX 768
#define LDH 2048
#define CSCL 4.8828125e-4f  // 2^-11

static __device__ __forceinline__ void gload16(const void* g, void* l) {
  __builtin_amdgcn_global_load_lds(
      (const __attribute__((address_space(1))) void*)g,
      (__attribute__((address_space(3))) void*)l, 16, 0, 0);
}

static __device__ __forceinline__ float sigmoidf_(float x) {
  return 1.f / (1.f + expf(-x));
}

static __device__ __forceinline__ unsigned short bc16(f16 x) {
  return __builtin_bit_cast(unsigned short, x);
}

// split v into l0 + l1*2^-11 (l1 stored scaled)
static __device__ __forceinline__ void split2(float v, f16& l0, f16& l1) {
  l0 = (f16)v;
  l1 = (f16)((v - (float)l0) * 2048.0f);
}

#define ACCZ(a)                                 \
  _Pragma("unroll") for (int i_ = 0; i_ < 2; ++i_) \
  _Pragma("unroll") for (int j_ = 0; j_ < 2; ++j_) \
  _Pragma("unroll") for (int e_ = 0; e_ < 16; ++e_) a[i_][j_][e_] = 0.f;

// ======== 2-limb f16 3-product GEMM core, 128x128 tile, 4 waves (2Mx2N),
// 32x32x16 MFMA (wave tile 64x64 = 2x2 of 32x32). dbuf staging, vmcnt(8).
// A: 128 rows stride lda, limb l at col (abase + l*aLS + k); B: 128 rows
// stride ldb, limb l at col (l*bLS + k). nkt = K/32. lds: 2 x 16384 f16.
static __device__ __forceinline__ void gemf(const f16* __restrict__ A, int lda,
                                            int aLS, int abase,
                                            const f16* __restrict__ B, int ldb,
                                            int bLS, int nkt, f16* lds,
                                            f32x16 (&aM)[2][2], f32x16 (&aC)[2][2]) {
  const int t = threadIdx.x;
  const int wave = t >> 6, lane = t & 63;
  const int wr = wave >> 1, wn = wave & 1;
  const int frow = lane & 31;               // row within 32-tile
  const int kh = lane >> 5;                 // k-half (8 f16)
  const int fswz = (frow >> 1) & 3;         // swizzle f(row)
  const int gs = (t & 3) ^ ((t >> 3) & 3);  // inverse-swizzled global slot

#define STG(buf, kt)                                                          \
  _Pragma("unroll") for (int lb = 0; lb < 2; ++lb)                            \
  _Pragma("unroll") for (int g = 0; g < 2; ++g) {                             \
    const int row_ = g * 64 + (t >> 2);                                       \
    gload16(A + (size_t)row_ * lda + abase + lb * aLS + (kt) * 32 + gs * 8,   \
            lds + (buf) * 16384 + lb * 4096 + g * 2048 + wave * 512);         \
    gload16(B + (size_t)row_ * ldb + lb * bLS + (kt) * 32 + gs * 8,           \
            lds + (buf) * 16384 + 8192 + lb * 4096 + g * 2048 + wave * 512);  \
  }

  STG(0, 0);
  for (int kt = 0; kt < nkt; ++kt) {
    const int cur = kt & 1;
    if (kt + 1 < nkt) {
      STG(cur ^ 1, kt + 1);
      asm volatile("s_waitcnt vmcnt(8)" ::: "memory");  // current buf landed
    } else {
      asm volatile("s_waitcnt vmcnt(0)" ::: "memory");
    }
    __builtin_amdgcn_s_barrier();
    asm volatile("" ::: "memory");

    const f16* bp = lds + cur * 16384;
    f16x8 a0[2][2], a1[2][2], b0[2][2], b1[2][2];
#pragma unroll
    for (int n = 0; n < 2; ++n)
#pragma unroll
      for (int ks = 0; ks < 2; ++ks) {
        const int row = wn * 64 + n * 32 + frow;
        const int slot = (ks * 2 + kh) ^ fswz;
        b0[n][ks] = *(const f16x8*)&bp[8192 + row * 32 + slot * 8];
        b1[n][ks] = *(const f16x8*)&bp[12288 + row * 32 + slot * 8];
      }
#pragma unroll
    for (int m = 0; m < 2; ++m)
#pragma unroll
      for (int ks = 0; ks < 2; ++ks) {
        const int row = wr * 64 + m * 32 + frow;
        const int slot = (ks * 2 + kh) ^ fswz;
        a0[m][ks] = *(const f16x8*)&bp[row * 32 + slot * 8];
        a1[m][ks] = *(const f16x8*)&bp[4096 + row * 32 + slot * 8];
      }
    __builtin_amdgcn_s_setprio(1);
    // cross products (scaled 2^11) -> accC
#pragma unroll
    for (int m = 0; m < 2; ++m)
#pragma unroll
      for (int n = 0; n < 2; ++n) {
#pragma unroll
        for (int ks = 0; ks < 2; ++ks)
          aC[m][n] = __builtin_amdgcn_mfma_f32_32x32x16_f16(a0[m][ks], b1[n][ks],
                                                            aC[m][n], 0, 0, 0);
#pragma unroll
        for (int ks = 0; ks < 2; ++ks)
          aC[m][n] = __builtin_amdgcn_mfma_f32_32x32x16_f16(a1[m][ks], b0[n][ks],
                                                            aC[m][n], 0, 0, 0);
      }
    // main product, k ascending -> accM
#pragma unroll
    for (int m = 0; m < 2; ++m)
#pragma unroll
      for (int n = 0; n < 2; ++n)
#pragma unroll
        for (int ks = 0; ks < 2; ++ks)
          aM[m][n] = __builtin_amdgcn_mfma_f32_32x32x16_f16(a0[m][ks], b0[n][ks],
                                                            aM[m][n], 0, 0, 0);
    __builtin_amdgcn_s_setprio(0);
    asm volatile("" ::: "memory");
    __builtin_amdgcn_s_barrier();  // all reads done -> buf reusable
  }
#undef STG
}

// 32x32 C/D layout (m74/m101): col = lane&31, row = (reg&3)+8*(reg>>2)+4*(lane>>5)
#define EPI32_IDX                                        \
  const int lane = threadIdx.x & 63;                     \
  const int wave = threadIdx.x >> 6;                     \
  const int rbw = (wave >> 1) * 64;                      \
  const int cbw = (wave & 1) * 64 + (lane & 31);         \
  const int kh_ = (lane >> 5) * 4;

// ================= adjacency: M=2048(in|out), N=4096, K=1024
__global__ __launch_bounds__(256, 2) void adjf(const f16* __restrict__ A2f,
                                               const f16* __restrict__ hN2f,
                                               f16* __restrict__ X2) {
  __shared__ f16 lds[32768];
  const int m0 = blockIdx.y * 128;
  const int n0 = blockIdx.x * 128;
  f32x16 aM[2][2], aC[2][2];
  ACCZ(aM);
  ACCZ(aC);
  gemf(A2f + (size_t)m0 * LDH, LDH, 1024, 0, hN2f + (size_t)n0 * LDH, LDH, 1024,
       32, lds, aM, aC);
  EPI32_IDX;
#pragma unroll
  for (int m = 0; m < 2; ++m)
#pragma unroll
    for (int n = 0; n < 2; ++n)
#pragma unroll
      for (int i = 0; i < 16; ++i) {
        const int gr = m0 + rbw + m * 32 + (i & 3) + 8 * (i >> 2) + kh_;
        const int gc = n0 + cbw + n * 32;
        const float v = aM[m][n][i] + aC[m][n][i] * CSCL;
        const int node = gr & 1023;
        const int coff = (gr >> 10) * 128;  // 0: m_in, 128: m_out
        const int bb = gc >> 7, d = gc & 127;
        f16* px = X2 + ((size_t)node * 32 + bb) * LDX + coff + d;
        f16 l0, l1;
        split2(v, l0, l1);
        px[0] = l0;
        px[384] = l1;
      }
}

// ================= dense (fused): bx=0 z-pre(W3+u3), bx=1 r-path(W4+u3)+ew1,
//                  bx=2 hv-pre(W5)
__global__ __launch_bounds__(256, 2) void densef(const f16* __restrict__ X2,
                                                 const f16* __restrict__ Wsm,
                                                 const f16* __restrict__ u3wb,
                                                 const float* __restrict__ u3b,
                                                 const float* __restrict__ w4b,
                                                 const float* __restrict__ h,
                                                 float* __restrict__ pre,
                                                 f16* __restrict__ rh2) {
  __shared__ f16 lds[32768];
  const int m0 = blockIdx.y * 128;
  const int bx = blockIdx.x;
  f32x16 aM[2][2], aC[2][2];
  ACCZ(aM);
  ACCZ(aC);
  if (bx == 2) {
    gemf(X2 + (size_t)m0 * LDX, LDX, 384, 0, Wsm + (size_t)256 * 512, 512, 256,
         8, lds, aM, aC);
  } else {
    gemf(X2 + (size_t)m0 * LDX, LDX, 384, 0, Wsm + (size_t)(bx * 128) * 512, 512, 256,
         8, lds, aM, aC);
    gemf(X2 + (size_t)m0 * LDX, LDX, 384, 256, u3wb, 256, 128, 4, lds, aM, aC);
  }
  EPI32_IDX;
#pragma unroll
  for (int m = 0; m < 2; ++m)
#pragma unroll
    for (int n = 0; n < 2; ++n)
#pragma unroll
      for (int i = 0; i < 16; ++i) {
        const int gr = m0 + rbw + m * 32 + (i & 3) + 8 * (i >> 2) + kh_;
        const int gc = cbw + n * 32;  // 0..127
        const float v = aM[m][n][i] + aC[m][n][i] * CSCL;
        if (bx == 0) {
          pre[(size_t)gr * 256 + gc] = v;  // z-pre (no biases)
        } else if (bx == 2) {
          pre[(size_t)gr * 256 + 128 + gc] = v;  // hv-pre
        } else {
          // fused ew1: r = sigmoid(v + w4b + u3b); rh = r*h -> 2-limb
          const float rr = sigmoidf_((v + w4b[gc]) + u3b[gc]);
          const int bb = gr & 31, node = gr >> 5;
          const float hh = h[((size_t)bb * 1024 + node) * 128 + gc];
          f16 l0, l1;
          split2(rr * hh, l0, l1);
          rh2[(size_t)gr * 256 + gc] = l0;
          rh2[(size_t)gr * 256 + 128 + gc] = l1;
        }
      }
}

// ================= u5 GEMM + fused ew2 epilogue (z, hv, h' -> out)
__global__ __launch_bounds__(256, 2) void u5g(const f16* __restrict__ rh2,
                                              const f16* __restrict__ u5wb,
                                              const float* __restrict__ pre,
                                              const float* __restrict__ h,
                                              const float* __restrict__ w3b,
                                              const float* __restrict__ u3b,
                                              const float* __restrict__ w5b,
                                              const float* __restrict__ u5b,
                                              float* __restrict__ out) {
  __shared__ f16 lds[32768];
  const int m0 = blockIdx.x * 128;
  f32x16 aM[2][2], aC[2][2];
  ACCZ(aM);
  ACCZ(aC);
  gemf(rh2 + (size_t)m0 * 256, 256, 128, 0, u5wb, 256, 128, 4, lds, aM, aC);
  EPI32_IDX;
#pragma unroll
  for (int m = 0; m < 2; ++m)
#pragma unroll
    for (int n = 0; n < 2; ++n)
#pragma unroll
      for (int i = 0; i < 16; ++i) {
        const int gr = m0 + rbw + m * 32 + (i & 3) + 8 * (i >> 2) + kh_;
        const int gc = cbw + n * 32;
        const float v = aM[m][n][i] + aC[m][n][i] * CSCL;
        const float u5f = v + u5b[gc];  // np: U5 + u5b
        const float z = sigmoidf_((pre[(size_t)gr * 256 + gc] + w3b[gc]) + u3b[gc]);
        const float hv = tanhf((pre[(size_t)gr * 256 + 128 + gc] + w5b[gc]) + u5f);
        const int bb = gr & 31, node = gr >> 5;
        const size_t hi = ((size_t)bb * 1024 + node) * 128 + gc;
        const float hh = h[hi];
        out[hi] = (1.f - z) * hh + z * hv;  // np: (1-z)*h + z*hv
      }
}

// ================= pack h (fp32 [B][N][D]) -> hN2f 2-limb + X2 h-cols 2-limb
__global__ __launch_bounds__(256) void pack_h(const float* __restrict__ h,
                                              f16* __restrict__ hN2f,
                                              f16* __restrict__ X2) {
  __shared__ unsigned int lds01[128][33];
  const int t = threadIdx.x;
  const int b = blockIdx.y;
  const int n0 = blockIdx.x * 32;
#pragma unroll
  for (int i = 0; i < 16; ++i) {
    const int idx = i * 256 + t;
    const int nl = idx >> 7, d = idx & 127;
    const float v = h[((size_t)b * 1024 + n0 + nl) * 128 + d];
    f16 l0, l1;
    split2(v, l0, l1);
    const size_t xr = ((size_t)(n0 + nl) * 32 + b) * LDX + 256 + d;
    X2[xr] = l0;
    X2[xr + 384] = l1;
    lds01[d][nl] = (unsigned)bc16(l0) | ((unsigned)bc16(l1) << 16);
  }
  __syncthreads();
#pragma unroll
  for (int i = 0; i < 16; ++i) {
    const int idx = i * 256 + t;
    const int d = idx >> 5, nl = idx & 31;
    const unsigned pk = lds01[d][nl];
    f16* row = hN2f + (size_t)(b * 128 + d) * LDH + n0 + nl;
    row[0] = __builtin_bit_cast(f16, (unsigned short)(pk & 0xffffu));
    row[1024] = __builtin_bit_cast(f16, (unsigned short)(pk >> 16));
  }
}

// ================= init kernels
__global__ __launch_bounds__(256) void split_adjf(const float* __restrict__ src,
                                                  f16* __restrict__ dst) {
  const int i = blockIdx.x * 256 + threadIdx.x;  // 1M
  const int r = i >> 10, c = i & 1023;
  f16 l0, l1;
  split2(src[i], l0, l1);
  dst[(size_t)r * LDH + c] = l0;
  dst[(size_t)r * LDH + 1024 + c] = l1;
}

__global__ void build_wsm(const float* __restrict__ w3, const float* __restrict__ w4,
                          const float* __restrict__ w5, f16* __restrict__ Wsm) {
  const int k = blockIdx.x * 128 + threadIdx.x;  // 0..255
  const int j = blockIdx.y;                      // 0..383
  float v;
  if (j < 128) v = w3[j * 256 + k];
  else if (j < 256) v = w4[(j - 128) * 256 + k];
  else v = w5[(j - 256) * 256 + k];
  f16 l0, l1;
  split2(v, l0, l1);
  Wsm[(size_t)j * 512 + k] = l0;
  Wsm[(size_t)j * 512 + 256 + k] = l1;
}

__global__ void build_uw(const float* __restrict__ u, f16* __restrict__ dst) {
  const int i = blockIdx.x * 256 + threadIdx.x;  // 16384
  const int j = i >> 7, k = i & 127;
  f16 l0, l1;
  split2(u[i], l0, l1);
  dst[(size_t)j * 256 + k] = l0;
  dst[(size_t)j * 256 + 128 + k] = l1;
}

__global__ void sentinel(float* out, int n) {
  const int i = blockIdx.x * 256 + threadIdx.x;
  if (i < n) out[i] = 123456789.f;
}

extern "C" void kernel_launch(void* const* d_in, const int* in_sizes, int n_in,
                              void* d_out, int out_size, void* d_ws, size_t ws_size,
                              hipStream_t stream) {
  const float* input = (const float*)d_in[0];
  const float* Ain = (const float*)d_in[1];
  const float* Aout = (const float*)d_in[2];
  const float* w3w = (const float*)d_in[3];
  const float* w3b = (const float*)d_in[4];
  const float* u3w = (const float*)d_in[5];
  const float* u3b = (const float*)d_in[6];
  const float* w4w = (const float*)d_in[7];
  const float* w4b = (const float*)d_in[8];
  const float* w5w = (const float*)d_in[9];
  const float* w5b = (const float*)d_in[10];
  const float* u5wf = (const float*)d_in[11];
  const float* u5b = (const float*)d_in[12];
  // d_in[13] = time_step; fixed at 5 by the problem spec.

  char* ws = (char*)d_ws;
  size_t off = 0;
  auto alloc = [&](size_t bytes) -> void* {
    void* p = ws + off;
    off += (bytes + 255) & ~(size_t)255;
    return p;
  };
  f16* A2f = (f16*)alloc(2048ull * LDH * 2);   // 8.39 MB
  f16* hN2f = (f16*)alloc(4096ull * LDH * 2);  // 16.78 MB (rh2 overlay)
  f16* X2 = (f16*)alloc(32768ull * LDX * 2);   // 50.33 MB
  f16* Wsm = (f16*)alloc(384ull * 512 * 2);
  f16* u3wb = (f16*)alloc(128ull * 256 * 2);
  f16* u5wb = (f16*)alloc(128ull * 256 * 2);
  float* pre = (float*)alloc(32768ull * 256 * 4);  // 33.55 MB (z|hv)
  f16* rh2 = hN2f;  // overlay: densef writes after adjf read hN2f; pack_h rewrites
  if (off > ws_size) {
    sentinel<<<dim3((out_size + 255) / 256), dim3(256), 0, stream>>>((float*)d_out, out_size);
    return;
  }

  split_adjf<<<dim3(4096), dim3(256), 0, stream>>>(Ain, A2f);
  split_adjf<<<dim3(4096), dim3(256), 0, stream>>>(Aout, A2f + 1024ull * LDH);
  build_wsm<<<dim3(2, 384), dim3(128), 0, stream>>>(w3w, w4w, w5w, Wsm);
  build_uw<<<dim3(64), dim3(256), 0, stream>>>(u3w, u3wb);
  build_uw<<<dim3(64), dim3(256), 0, stream>>>(u5wf, u5wb);

  float* out = (float*)d_out;
  const float* h = input;
  for (int step = 0; step < 5; ++step) {
    pack_h<<<dim3(32, 32), dim3(256), 0, stream>>>(h, hN2f, X2);
    adjf<<<dim3(32, 16), dim3(256), 0, stream>>>(A2f, hN2f, X2);
    densef<<<dim3(3, 256), dim3(256), 0, stream>>>(X2, Wsm, u3wb, u3b, w4b, h, pre, rh2);
    u5g<<<dim3(256), dim3(256), 0, stream>>>(rh2, u5wb, pre, h, w3b, u3b, w5b, u5b, out);
    h = out;
  }
}

// Round 11
// 748.486 us; speedup vs baseline: 1.1474x; 1.1474x over previous
//
#include <hip/hip_runtime.h>
#include <cstdint>
#include <cstddef>

// GGNN on MI355X. Round 11: r9 structure restored (densef/ew1/u5g at proven r9
// form); numerics = 2-limb f16 (UNSCALED l1; subnormal loss <=2^-24 << 2^-22
// truncation), 3 products {01,10,00} in ONE accumulator (corrections first,
// main last k-ascending). adjf upgraded to 64x128 wave tiles (128x256 block,
// 1 block/CU, -25% ds_read per FLOP). Slot-XOR swizzle (verified involution).
// Layouts:
//   A2f [2048: Ain|Aout][ l0(1024) | l1(1024) ]
//   hN2f[b*128+d][ l0 | l1 ]  (rh2 overlay)
//   X2  [n*32+b][ l0: m_in(128) m_out(128) h(128) | l1 same ]  (LDX 768)
//   Wsm [384: w3|w4|w5][ l0(256)|l1(256) ]; u3wb/u5wb [128][ l0|l1 (128) ]
//   pre [32768][384] fp32 (z|r|hv pre-acts, no biases); u3f [32768][128]

typedef _Float16 f16;
typedef __attribute__((ext_vector_type(8))) _Float16 f16x8;
typedef __attribute__((ext_vector_type(4))) float f32x4;

#define LDX 768
#define LDH 2048

static __device__ __forceinline__ void gload16(const void* g, void* l) {
  __builtin_amdgcn_global_load_lds(
      (const __attribute__((address_space(1))) void*)g,
      (__attribute__((address_space(3))) void*)l, 16, 0, 0);
}

static __device__ __forceinline__ float sigmoidf_(float x) {
  return 1.f / (1.f + expf(-x));
}

static __device__ __forceinline__ unsigned short bc16(f16 x) {
  return __builtin_bit_cast(unsigned short, x);
}

// split v into l0 + l1 (unscaled; l1 may be subnormal - loss <= 2^-24)
static __device__ __forceinline__ void split2(float v, f16& l0, f16& l1) {
  l0 = (f16)v;
  l1 = (f16)(v - (float)l0);
}

// ======== gemfN: 2-limb f16 3-product GEMM, 128x128 tile, 4 waves (2Mx2N,
// wave 64x64, 16x16x32 MFMA), dbuf 64KB, vmcnt(8). Single accumulator:
// per kt: cross a0*b1, a1*b0, then main a0*b0 (k ascending).
static __device__ __forceinline__ void gemfN(const f16* __restrict__ A, int lda,
                                             int aLS, int abase,
                                             const f16* __restrict__ B, int ldb,
                                             int bLS, int nkt, f16* lds,
                                             f32x4 (&acc)[4][4]) {
  const int t = threadIdx.x;
  const int wave = t >> 6, lane = t & 63;
  const int wr = wave >> 1, wn = wave & 1;
  const int frow = lane & 15;
  const int fk = lane >> 4;
  const int sl = fk ^ ((frow >> 1) & 3);
  const int gs = (t & 3) ^ ((t >> 3) & 3);

#define STGN(buf, kt)                                                         \
  _Pragma("unroll") for (int lb = 0; lb < 2; ++lb)                            \
  _Pragma("unroll") for (int g = 0; g < 2; ++g) {                             \
    const int row_ = g * 64 + (t >> 2);                                       \
    gload16(A + (size_t)row_ * lda + abase + lb * aLS + (kt) * 32 + gs * 8,   \
            lds + (buf) * 16384 + lb * 4096 + g * 2048 + wave * 512);         \
    gload16(B + (size_t)row_ * ldb + lb * bLS + (kt) * 32 + gs * 8,           \
            lds + (buf) * 16384 + 8192 + lb * 4096 + g * 2048 + wave * 512);  \
  }

  STGN(0, 0);
  for (int kt = 0; kt < nkt; ++kt) {
    const int cur = kt & 1;
    if (kt + 1 < nkt) {
      STGN(cur ^ 1, kt + 1);
      asm volatile("s_waitcnt vmcnt(8)" ::: "memory");
    } else {
      asm volatile("s_waitcnt vmcnt(0)" ::: "memory");
    }
    __builtin_amdgcn_s_barrier();
    asm volatile("" ::: "memory");

    const f16* bp = lds + cur * 16384;
    f16x8 a0[4], a1[4], b0[4], b1[4];
#pragma unroll
    for (int nf = 0; nf < 4; ++nf) {
      const int row = wn * 64 + nf * 16 + frow;
      b0[nf] = *(const f16x8*)&bp[8192 + row * 32 + sl * 8];
      b1[nf] = *(const f16x8*)&bp[12288 + row * 32 + sl * 8];
    }
#pragma unroll
    for (int mf = 0; mf < 4; ++mf) {
      const int row = wr * 64 + mf * 16 + frow;
      a0[mf] = *(const f16x8*)&bp[row * 32 + sl * 8];
      a1[mf] = *(const f16x8*)&bp[4096 + row * 32 + sl * 8];
    }
    __builtin_amdgcn_s_setprio(1);
#pragma unroll
    for (int mf = 0; mf < 4; ++mf)
#pragma unroll
      for (int nf = 0; nf < 4; ++nf)
        acc[mf][nf] = __builtin_amdgcn_mfma_f32_16x16x32_f16(a0[mf], b1[nf],
                                                             acc[mf][nf], 0, 0, 0);
#pragma unroll
    for (int mf = 0; mf < 4; ++mf)
#pragma unroll
      for (int nf = 0; nf < 4; ++nf)
        acc[mf][nf] = __builtin_amdgcn_mfma_f32_16x16x32_f16(a1[mf], b0[nf],
                                                             acc[mf][nf], 0, 0, 0);
#pragma unroll
    for (int mf = 0; mf < 4; ++mf)
#pragma unroll
      for (int nf = 0; nf < 4; ++nf)
        acc[mf][nf] = __builtin_amdgcn_mfma_f32_16x16x32_f16(a0[mf], b0[nf],
                                                             acc[mf][nf], 0, 0, 0);
    __builtin_amdgcn_s_setprio(0);
    asm volatile("" ::: "memory");
    __builtin_amdgcn_s_barrier();
  }
#undef STGN
}

// ======== gemfW: wide-N variant for adjacency. 128x256 block, 4 waves (2Mx2N,
// wave 64x128), dbuf 2x24K f16 = 96KB (1 block/CU), vmcnt(12).
// 24 ds_read per 96 MFMA per kt (-25% reads/FLOP vs gemfN).
static __device__ __forceinline__ void gemfW(const f16* __restrict__ A, int lda,
                                             int aLS,
                                             const f16* __restrict__ B, int ldb,
                                             int bLS, int nkt, f16* lds,
                                             f32x4 (&acc)[4][8]) {
  const int t = threadIdx.x;
  const int wave = t >> 6, lane = t & 63;
  const int wrm = wave >> 1, wnn = wave & 1;
  const int frow = lane & 15;
  const int fk = lane >> 4;
  const int sl = fk ^ ((frow >> 1) & 3);
  const int gs = (t & 3) ^ ((t >> 3) & 3);
  // LDS per buf (24576 f16): A limb lb at lb*4096 (128x32); B at 8192 + lb*8192 (256x32)

#define STGW(buf, kt)                                                         \
  _Pragma("unroll") for (int lb = 0; lb < 2; ++lb)                            \
  _Pragma("unroll") for (int g = 0; g < 2; ++g) {                             \
    const int row_ = g * 64 + (t >> 2);                                       \
    gload16(A + (size_t)row_ * lda + lb * aLS + (kt) * 32 + gs * 8,           \
            lds + (buf) * 24576 + lb * 4096 + g * 2048 + wave * 512);         \
  }                                                                           \
  _Pragma("unroll") for (int lb = 0; lb < 2; ++lb)                            \
  _Pragma("unroll") for (int g = 0; g < 4; ++g) {                             \
    const int row_ = g * 64 + (t >> 2);                                       \
    gload16(B + (size_t)row_ * ldb + lb * bLS + (kt) * 32 + gs * 8,           \
            lds + (buf) * 24576 + 8192 + lb * 8192 + g * 2048 + wave * 512);  \
  }

  STGW(0, 0);
  for (int kt = 0; kt < nkt; ++kt) {
    const int cur = kt & 1;
    if (kt + 1 < nkt) {
      STGW(cur ^ 1, kt + 1);
      asm volatile("s_waitcnt vmcnt(12)" ::: "memory");
    } else {
      asm volatile("s_waitcnt vmcnt(0)" ::: "memory");
    }
    __builtin_amdgcn_s_barrier();
    asm volatile("" ::: "memory");

    const f16* bp = lds + cur * 24576;
    f16x8 a0[4], a1[4], b0[8], b1[8];
#pragma unroll
    for (int mf = 0; mf < 4; ++mf) {
      const int row = wrm * 64 + mf * 16 + frow;
      a0[mf] = *(const f16x8*)&bp[row * 32 + sl * 8];
      a1[mf] = *(const f16x8*)&bp[4096 + row * 32 + sl * 8];
    }
#pragma unroll
    for (int nf = 0; nf < 8; ++nf) {
      const int row = wnn * 128 + nf * 16 + frow;
      b0[nf] = *(const f16x8*)&bp[8192 + row * 32 + sl * 8];
      b1[nf] = *(const f16x8*)&bp[16384 + row * 32 + sl * 8];
    }
    __builtin_amdgcn_s_setprio(1);
#pragma unroll
    for (int mf = 0; mf < 4; ++mf)
#pragma unroll
      for (int nf = 0; nf < 8; ++nf)
        acc[mf][nf] = __builtin_amdgcn_mfma_f32_16x16x32_f16(a0[mf], b1[nf],
                                                             acc[mf][nf], 0, 0, 0);
#pragma unroll
    for (int mf = 0; mf < 4; ++mf)
#pragma unroll
      for (int nf = 0; nf < 8; ++nf)
        acc[mf][nf] = __builtin_amdgcn_mfma_f32_16x16x32_f16(a1[mf], b0[nf],
                                                             acc[mf][nf], 0, 0, 0);
#pragma unroll
    for (int mf = 0; mf < 4; ++mf)
#pragma unroll
      for (int nf = 0; nf < 8; ++nf)
        acc[mf][nf] = __builtin_amdgcn_mfma_f32_16x16x32_f16(a0[mf], b0[nf],
                                                             acc[mf][nf], 0, 0, 0);
    __builtin_amdgcn_s_setprio(0);
    asm volatile("" ::: "memory");
    __builtin_amdgcn_s_barrier();
  }
#undef STGW
}

#define ACCZ4(a)                                   \
  _Pragma("unroll") for (int i_ = 0; i_ < 4; ++i_) \
  _Pragma("unroll") for (int j_ = 0; j_ < 4; ++j_) a[i_][j_] = {0.f, 0.f, 0.f, 0.f};
#define ACCZ8(a)                                   \
  _Pragma("unroll") for (int i_ = 0; i_ < 4; ++i_) \
  _Pragma("unroll") for (int j_ = 0; j_ < 8; ++j_) a[i_][j_] = {0.f, 0.f, 0.f, 0.f};

// ================= adjacency: M=2048(in|out), N=4096, K=1024, wide tiles
__global__ __launch_bounds__(256, 1) void adjf(const f16* __restrict__ A2f,
                                               const f16* __restrict__ hN2f,
                                               f16* __restrict__ X2) {
  __shared__ f16 lds[49152];
  const int m0 = blockIdx.y * 128;
  const int n0 = blockIdx.x * 256;
  f32x4 acc[4][8];
  ACCZ8(acc);
  gemfW(A2f + (size_t)m0 * LDH, LDH, 1024, hN2f + (size_t)n0 * LDH, LDH, 1024,
        32, lds, acc);

  const int lane = threadIdx.x & 63, wave = threadIdx.x >> 6;
  const int rb = m0 + (wave >> 1) * 64 + (lane >> 4) * 4;
  const int cb = n0 + (wave & 1) * 128 + (lane & 15);
#pragma unroll
  for (int mf = 0; mf < 4; ++mf)
#pragma unroll
    for (int nf = 0; nf < 8; ++nf)
#pragma unroll
      for (int j = 0; j < 4; ++j) {
        const int gr = rb + mf * 16 + j;
        const int gc = cb + nf * 16;
        const float v = acc[mf][nf][j];
        const int node = gr & 1023;
        const int coff = (gr >> 10) * 128;  // 0: m_in, 128: m_out
        const int bb = gc >> 7, d = gc & 127;
        f16* px = X2 + ((size_t)node * 32 + bb) * LDX + coff + d;
        f16 l0, l1;
        split2(v, l0, l1);
        px[0] = l0;
        px[384] = l1;
      }
}

// ================= dense (r9 form): bx<3 -> pre[.][bx*128..]; bx==3 -> u3f
__global__ __launch_bounds__(256, 2) void densef(const f16* __restrict__ X2,
                                                 const f16* __restrict__ Wsm,
                                                 const f16* __restrict__ u3wb,
                                                 const float* __restrict__ u3b,
                                                 float* __restrict__ pre,
                                                 float* __restrict__ u3f) {
  __shared__ f16 lds[32768];
  const int m0 = blockIdx.y * 128;
  const int bx = blockIdx.x;
  f32x4 acc[4][4];
  ACCZ4(acc);
  const int lane = threadIdx.x & 63, wave = threadIdx.x >> 6;
  const int rb = m0 + (wave >> 1) * 64 + (lane >> 4) * 4;
  const int cb = (wave & 1) * 64 + (lane & 15);
  if (bx < 3) {
    gemfN(X2 + (size_t)m0 * LDX, LDX, 384, 0, Wsm + (size_t)bx * 128 * 512, 512, 256,
          8, lds, acc);
#pragma unroll
    for (int mf = 0; mf < 4; ++mf)
#pragma unroll
      for (int nf = 0; nf < 4; ++nf)
#pragma unroll
        for (int j = 0; j < 4; ++j)
          pre[(size_t)(rb + mf * 16 + j) * 384 + bx * 128 + cb + nf * 16] =
              acc[mf][nf][j];
  } else {
    gemfN(X2 + (size_t)m0 * LDX, LDX, 384, 256, u3wb, 256, 128, 4, lds, acc);
#pragma unroll
    for (int mf = 0; mf < 4; ++mf)
#pragma unroll
      for (int nf = 0; nf < 4; ++nf)
#pragma unroll
        for (int j = 0; j < 4; ++j) {
          const int gc = cb + nf * 16;
          // np: u3 = (h@u3w^T) + u3b, rounded once
          u3f[(size_t)(rb + mf * 16 + j) * 128 + gc] = acc[mf][nf][j] + u3b[gc];
        }
  }
}

// ================= u5 GEMM + fused ew2 epilogue (r9 form)
__global__ __launch_bounds__(256, 2) void u5g(const f16* __restrict__ rh2,
                                              const f16* __restrict__ u5wb,
                                              const float* __restrict__ pre,
                                              const float* __restrict__ u3f,
                                              const float* __restrict__ h,
                                              const float* __restrict__ w3b,
                                              const float* __restrict__ w5b,
                                              const float* __restrict__ u5b,
                                              float* __restrict__ out) {
  __shared__ f16 lds[32768];
  const int m0 = blockIdx.x * 128;
  f32x4 acc[4][4];
  ACCZ4(acc);
  gemfN(rh2 + (size_t)m0 * 256, 256, 128, 0, u5wb, 256, 128, 4, lds, acc);

  const int lane = threadIdx.x & 63, wave = threadIdx.x >> 6;
  const int rb = m0 + (wave >> 1) * 64 + (lane >> 4) * 4;
  const int cb = (wave & 1) * 64 + (lane & 15);
#pragma unroll
  for (int mf = 0; mf < 4; ++mf)
#pragma unroll
    for (int nf = 0; nf < 4; ++nf)
#pragma unroll
      for (int j = 0; j < 4; ++j) {
        const int gr = rb + mf * 16 + j;
        const int gc = cb + nf * 16;
        const float u5f = acc[mf][nf][j] + u5b[gc];  // np: U5 + u5b
        const float z = sigmoidf_((pre[(size_t)gr * 384 + gc] + w3b[gc]) +
                                  u3f[(size_t)gr * 128 + gc]);
        const float hv = tanhf((pre[(size_t)gr * 384 + 256 + gc] + w5b[gc]) + u5f);
        const int bb = gr & 31, node = gr >> 5;
        const size_t hi = ((size_t)bb * 1024 + node) * 128 + gc;
        const float hh = h[hi];
        out[hi] = (1.f - z) * hh + z * hv;  // np: (1-z)*h + z*hv
      }
}

// ================= pack h (fp32 [B][N][D]) -> hN2f 2-limb + X2 h-cols 2-limb
__global__ __launch_bounds__(256) void pack_h(const float* __restrict__ h,
                                              f16* __restrict__ hN2f,
                                              f16* __restrict__ X2) {
  __shared__ unsigned int lds01[128][33];
  const int t = threadIdx.x;
  const int b = blockIdx.y;
  const int n0 = blockIdx.x * 32;
#pragma unroll
  for (int i = 0; i < 16; ++i) {
    const int idx = i * 256 + t;
    const int nl = idx >> 7, d = idx & 127;
    const float v = h[((size_t)b * 1024 + n0 + nl) * 128 + d];
    f16 l0, l1;
    split2(v, l0, l1);
    const size_t xr = ((size_t)(n0 + nl) * 32 + b) * LDX + 256 + d;
    X2[xr] = l0;
    X2[xr + 384] = l1;
    lds01[d][nl] = (unsigned)bc16(l0) | ((unsigned)bc16(l1) << 16);
  }
  __syncthreads();
#pragma unroll
  for (int i = 0; i < 16; ++i) {
    const int idx = i * 256 + t;
    const int d = idx >> 5, nl = idx & 31;
    const unsigned pk = lds01[d][nl];
    f16* row = hN2f + (size_t)(b * 128 + d) * LDH + n0 + nl;
    row[0] = __builtin_bit_cast(f16, (unsigned short)(pk & 0xffffu));
    row[1024] = __builtin_bit_cast(f16, (unsigned short)(pk >> 16));
  }
}

// ================= elementwise: r gate -> rh2 (2-limb f16, r9 form)
__global__ __launch_bounds__(256) void ew1(const float* __restrict__ pre,
                                           const float* __restrict__ u3f,
                                           const float* __restrict__ h,
                                           const float* __restrict__ w4b,
                                           f16* __restrict__ rh2) {
  const int e4 = blockIdx.x * 256 + threadIdx.x;
  const int r = e4 >> 5;
  const int dq = (e4 & 31) * 4;
  const int b = r & 31, n = r >> 5;
  const f32x4 p = *(const f32x4*)(pre + (size_t)r * 384 + 128 + dq);
  const f32x4 uf = *(const f32x4*)(u3f + (size_t)r * 128 + dq);
  const f32x4 hh = *(const f32x4*)(h + ((size_t)b * 1024 + n) * 128 + dq);
  const f32x4 b4 = *(const f32x4*)(w4b + dq);
  f16 o0[4], o1[4];
#pragma unroll
  for (int j = 0; j < 4; ++j) {
    const float rr = sigmoidf_((p[j] + b4[j]) + uf[j]);
    const float v = rr * hh[j];
    split2(v, o0[j], o1[j]);
  }
  *(ulong1*)&rh2[(size_t)r * 256 + dq] = *(ulong1*)o0;
  *(ulong1*)&rh2[(size_t)r * 256 + 128 + dq] = *(ulong1*)o1;
}

// ================= init kernels
__global__ __launch_bounds__(256) void split_adjf(const float* __restrict__ src,
                                                  f16* __restrict__ dst) {
  const int i = blockIdx.x * 256 + threadIdx.x;  // 1M
  const int r = i >> 10, c = i & 1023;
  f16 l0, l1;
  split2(src[i], l0, l1);
  dst[(size_t)r * LDH + c] = l0;
  dst[(size_t)r * LDH + 1024 + c] = l1;
}

__global__ void build_wsm(const float* __restrict__ w3, const float* __restrict__ w4,
                          const float* __restrict__ w5, f16* __restrict__ Wsm) {
  const int k = blockIdx.x * 128 + threadIdx.x;  // 0..255
  const int j = blockIdx.y;                      // 0..383
  float v;
  if (j < 128) v = w3[j * 256 + k];
  else if (j < 256) v = w4[(j - 128) * 256 + k];
  else v = w5[(j - 256) * 256 + k];
  f16 l0, l1;
  split2(v, l0, l1);
  Wsm[(size_t)j * 512 + k] = l0;
  Wsm[(size_t)j * 512 + 256 + k] = l1;
}

__global__ void build_uw(const float* __restrict__ u, f16* __restrict__ dst) {
  const int i = blockIdx.x * 256 + threadIdx.x;  // 16384
  const int j = i >> 7, k = i & 127;
  f16 l0, l1;
  split2(u[i], l0, l1);
  dst[(size_t)j * 256 + k] = l0;
  dst[(size_t)j * 256 + 128 + k] = l1;
}

__global__ void sentinel(float* out, int n) {
  const int i = blockIdx.x * 256 + threadIdx.x;
  if (i < n) out[i] = 123456789.f;
}

extern "C" void kernel_launch(void* const* d_in, const int* in_sizes, int n_in,
                              void* d_out, int out_size, void* d_ws, size_t ws_size,
                              hipStream_t stream) {
  const float* input = (const float*)d_in[0];
  const float* Ain = (const float*)d_in[1];
  const float* Aout = (const float*)d_in[2];
  const float* w3w = (const float*)d_in[3];
  const float* w3b = (const float*)d_in[4];
  const float* u3w = (const float*)d_in[5];
  const float* u3b = (const float*)d_in[6];
  const float* w4w = (const float*)d_in[7];
  const float* w4b = (const float*)d_in[8];
  const float* w5w = (const float*)d_in[9];
  const float* w5b = (const float*)d_in[10];
  const float* u5wf = (const float*)d_in[11];
  const float* u5b = (const float*)d_in[12];
  // d_in[13] = time_step; fixed at 5 by the problem spec.

  char* ws = (char*)d_ws;
  size_t off = 0;
  auto alloc = [&](size_t bytes) -> void* {
    void* p = ws + off;
    off += (bytes + 255) & ~(size_t)255;
    return p;
  };
  f16* A2f = (f16*)alloc(2048ull * LDH * 2);   // 8.39 MB
  f16* hN2f = (f16*)alloc(4096ull * LDH * 2);  // 16.78 MB (rh2 overlay)
  f16* X2 = (f16*)alloc(32768ull * LDX * 2);   // 50.33 MB
  f16* Wsm = (f16*)alloc(384ull * 512 * 2);
  f16* u3wb = (f16*)alloc(128ull * 256 * 2);
  f16* u5wb = (f16*)alloc(128ull * 256 * 2);
  float* pre = (float*)alloc(32768ull * 384 * 4);  // 50.33 MB
  float* u3f = (float*)alloc(32768ull * 128 * 4);  // 16.78 MB
  f16* rh2 = hN2f;  // overlay: ew1 writes after adjf read hN2f; pack_h rewrites
  if (off > ws_size) {
    sentinel<<<dim3((out_size + 255) / 256), dim3(256), 0, stream>>>((float*)d_out, out_size);
    return;
  }

  split_adjf<<<dim3(4096), dim3(256), 0, stream>>>(Ain, A2f);
  split_adjf<<<dim3(4096), dim3(256), 0, stream>>>(Aout, A2f + 1024ull * LDH);
  build_wsm<<<dim3(2, 384), dim3(128), 0, stream>>>(w3w, w4w, w5w, Wsm);
  build_uw<<<dim3(64), dim3(256), 0, stream>>>(u3w, u3wb);
  build_uw<<<dim3(64), dim3(256), 0, stream>>>(u5wf, u5wb);

  float* out = (float*)d_out;
  const float* h = input;
  for (int step = 0; step < 5; ++step) {
    pack_h<<<dim3(32, 32), dim3(256), 0, stream>>>(h, hN2f, X2);
    // adjacency: 128x256 tiles, grid 16x16 = 256 blocks (1/CU)
    adjf<<<dim3(16, 16), dim3(256), 0, stream>>>(A2f, hN2f, X2);
    densef<<<dim3(4, 256), dim3(256), 0, stream>>>(X2, Wsm, u3wb, u3b, pre, u3f);
    ew1<<<dim3(4096), dim3(256), 0, stream>>>(pre, u3f, h, w4b, rh2);
    u5g<<<dim3(256), dim3(256), 0, stream>>>(rh2, u5wb, pre, u3f, h, w3b, w5b, u5b, out);
    h = out;
  }
}

// Round 12
// 696.608 us; speedup vs baseline: 1.2328x; 1.0745x over previous
//
#include <hip/hip_runtime.h>
#include <cstdint>
#include <cstddef>

// GGNN on MI355X. Round 12: exact r9 configuration (689us, absmax 0.0249)
// restored — 2-limb f16 with l1 PRE-SCALED by 2^11 (r11 proved unscaled l1
// loses entire limb to MFMA denormal flush: absmax 0.0918), products
// {01,10} -> accC, {00} -> accM, v = accM + accC*2^-11; adjf 128x128 tiles
// at 2 blocks/CU (r11 proved wide 128x256 @1/CU regresses: lost cross-block
// overlap). ONE new change: ew1 fused into u5g (u5gf) — each block computes
// its rh2 tile (row-local: pre r-slice + u3f + h) straight into LDS in ew1's
// exact op order and the staging-swizzle layout, then GEMMs from LDS.
// Deletes ew1 dispatch + rh2 global round-trip. Bit-identical numerics.
// Layouts:
//   A2f [2048: Ain|Aout][ l0(1024) | l1'(1024) ]
//   hN2f[b*128+d][ l0 | l1' ]
//   X2  [n*32+b][ l0: m_in(128) m_out(128) h(128) | l1' same ]  (LDX 768)
//   Wsm [384: w3|w4|w5][ l0(256)|l1'(256) ]; u3wb/u5wb [128][ l0|l1' (128) ]

typedef _Float16 f16;
typedef __attribute__((ext_vector_type(8))) _Float16 f16x8;
typedef __attribute__((ext_vector_type(4))) float f32x4;

#define LDX 768
#define LDH 2048
#define CSCL 4.8828125e-4f  // 2^-11

static __device__ __forceinline__ void gload16(const void* g, void* l) {
  __builtin_amdgcn_global_load_lds(
      (const __attribute__((address_space(1))) void*)g,
      (__attribute__((address_space(3))) void*)l, 16, 0, 0);
}

static __device__ __forceinline__ float sigmoidf_(float x) {
  return 1.f / (1.f + expf(-x));
}

static __device__ __forceinline__ unsigned short bc16(f16 x) {
  return __builtin_bit_cast(unsigned short, x);
}

// split v into l0 + l1*2^-11 (l1 stored scaled; avoids f16 subnormals)
static __device__ __forceinline__ void split2(float v, f16& l0, f16& l1) {
  l0 = (f16)v;
  l1 = (f16)((v - (float)l0) * 2048.0f);
}

// ======== 2-limb f16 3-product GEMM core (r9-verified), 128x128 tile,
// 4 waves (2Mx2N, wave 64x64, 16x16x32 MFMA), dbuf 64KB, vmcnt(8).
static __device__ __forceinline__ void gemf(const f16* __restrict__ A, int lda,
                                            int aLS, int abase,
                                            const f16* __restrict__ B, int ldb,
                                            int bLS, int nkt, f16* lds,
                                            f32x4 (&aM)[4][4], f32x4 (&aC)[4][4]) {
  const int t = threadIdx.x;
  const int wave = t >> 6, lane = t & 63;
  const int wr = wave >> 1, wn = wave & 1;
  const int frow = lane & 15;
  const int fk = lane >> 4;
  const int sl = fk ^ ((frow >> 1) & 3);
  const int gs = (t & 3) ^ ((t >> 3) & 3);

#define STG(buf, kt)                                                          \
  _Pragma("unroll") for (int lb = 0; lb < 2; ++lb)                            \
  _Pragma("unroll") for (int g = 0; g < 2; ++g) {                             \
    const int row_ = g * 64 + (t >> 2);                                       \
    gload16(A + (size_t)row_ * lda + abase + lb * aLS + (kt) * 32 + gs * 8,   \
            lds + (buf) * 16384 + lb * 4096 + g * 2048 + wave * 512);         \
    gload16(B + (size_t)row_ * ldb + lb * bLS + (kt) * 32 + gs * 8,           \
            lds + (buf) * 16384 + 8192 + lb * 4096 + g * 2048 + wave * 512);  \
  }

  STG(0, 0);
  for (int kt = 0; kt < nkt; ++kt) {
    const int cur = kt & 1;
    if (kt + 1 < nkt) {
      STG(cur ^ 1, kt + 1);
      asm volatile("s_waitcnt vmcnt(8)" ::: "memory");
    } else {
      asm volatile("s_waitcnt vmcnt(0)" ::: "memory");
    }
    __builtin_amdgcn_s_barrier();
    asm volatile("" ::: "memory");

    const f16* bp = lds + cur * 16384;
    f16x8 a0[4], a1[4], b0[4], b1[4];
#pragma unroll
    for (int nf = 0; nf < 4; ++nf) {
      const int row = wn * 64 + nf * 16 + frow;
      b0[nf] = *(const f16x8*)&bp[8192 + row * 32 + sl * 8];
      b1[nf] = *(const f16x8*)&bp[12288 + row * 32 + sl * 8];
    }
#pragma unroll
    for (int mf = 0; mf < 4; ++mf) {
      const int row = wr * 64 + mf * 16 + frow;
      a0[mf] = *(const f16x8*)&bp[row * 32 + sl * 8];
      a1[mf] = *(const f16x8*)&bp[4096 + row * 32 + sl * 8];
    }
    __builtin_amdgcn_s_setprio(1);
#pragma unroll
    for (int mf = 0; mf < 4; ++mf)
#pragma unroll
      for (int nf = 0; nf < 4; ++nf) {
        aC[mf][nf] = __builtin_amdgcn_mfma_f32_16x16x32_f16(a0[mf], b1[nf],
                                                            aC[mf][nf], 0, 0, 0);
        aC[mf][nf] = __builtin_amdgcn_mfma_f32_16x16x32_f16(a1[mf], b0[nf],
                                                            aC[mf][nf], 0, 0, 0);
      }
#pragma unroll
    for (int mf = 0; mf < 4; ++mf)
#pragma unroll
      for (int nf = 0; nf < 4; ++nf)
        aM[mf][nf] = __builtin_amdgcn_mfma_f32_16x16x32_f16(a0[mf], b0[nf],
                                                            aM[mf][nf], 0, 0, 0);
    __builtin_amdgcn_s_setprio(0);
    asm volatile("" ::: "memory");
    __builtin_amdgcn_s_barrier();
  }
#undef STG
}

#define ACCZ4(a)                                   \
  _Pragma("unroll") for (int i_ = 0; i_ < 4; ++i_) \
  _Pragma("unroll") for (int j_ = 0; j_ < 4; ++j_) a[i_][j_] = {0.f, 0.f, 0.f, 0.f};

// ================= adjacency: M=2048(in|out), N=4096, K=1024 (r9 form)
__global__ __launch_bounds__(256, 2) void adjf(const f16* __restrict__ A2f,
                                               const f16* __restrict__ hN2f,
                                               f16* __restrict__ X2) {
  __shared__ f16 lds[32768];
  const int m0 = blockIdx.y * 128;
  const int n0 = blockIdx.x * 128;
  f32x4 aM[4][4], aC[4][4];
  ACCZ4(aM);
  ACCZ4(aC);
  gemf(A2f + (size_t)m0 * LDH, LDH, 1024, 0, hN2f + (size_t)n0 * LDH, LDH, 1024,
       32, lds, aM, aC);

  const int lane = threadIdx.x & 63, wave = threadIdx.x >> 6;
  const int rb = m0 + (wave >> 1) * 64 + (lane >> 4) * 4;
  const int cb = n0 + (wave & 1) * 64 + (lane & 15);
#pragma unroll
  for (int mf = 0; mf < 4; ++mf)
#pragma unroll
    for (int nf = 0; nf < 4; ++nf)
#pragma unroll
      for (int j = 0; j < 4; ++j) {
        const int gr = rb + mf * 16 + j;
        const int gc = cb + nf * 16;
        const float v = aM[mf][nf][j] + aC[mf][nf][j] * CSCL;
        const int node = gr & 1023;
        const int coff = (gr >> 10) * 128;  // 0: m_in, 128: m_out
        const int bb = gc >> 7, d = gc & 127;
        f16* px = X2 + ((size_t)node * 32 + bb) * LDX + coff + d;
        f16 l0, l1;
        split2(v, l0, l1);
        px[0] = l0;
        px[384] = l1;
      }
}

// ================= dense (r9 form): bx<3 -> pre[.][bx*128..]; bx==3 -> u3f
__global__ __launch_bounds__(256, 2) void densef(const f16* __restrict__ X2,
                                                 const f16* __restrict__ Wsm,
                                                 const f16* __restrict__ u3wb,
                                                 const float* __restrict__ u3b,
                                                 float* __restrict__ pre,
                                                 float* __restrict__ u3f) {
  __shared__ f16 lds[32768];
  const int m0 = blockIdx.y * 128;
  const int bx = blockIdx.x;
  f32x4 aM[4][4], aC[4][4];
  ACCZ4(aM);
  ACCZ4(aC);
  const int lane = threadIdx.x & 63, wave = threadIdx.x >> 6;
  const int rb = m0 + (wave >> 1) * 64 + (lane >> 4) * 4;
  const int cb = (wave & 1) * 64 + (lane & 15);
  if (bx < 3) {
    gemf(X2 + (size_t)m0 * LDX, LDX, 384, 0, Wsm + (size_t)bx * 128 * 512, 512, 256,
         8, lds, aM, aC);
#pragma unroll
    for (int mf = 0; mf < 4; ++mf)
#pragma unroll
      for (int nf = 0; nf < 4; ++nf)
#pragma unroll
        for (int j = 0; j < 4; ++j)
          pre[(size_t)(rb + mf * 16 + j) * 384 + bx * 128 + cb + nf * 16] =
              aM[mf][nf][j] + aC[mf][nf][j] * CSCL;
  } else {
    gemf(X2 + (size_t)m0 * LDX, LDX, 384, 256, u3wb, 256, 128, 4, lds, aM, aC);
#pragma unroll
    for (int mf = 0; mf < 4; ++mf)
#pragma unroll
      for (int nf = 0; nf < 4; ++nf)
#pragma unroll
        for (int j = 0; j < 4; ++j) {
          const int gc = cb + nf * 16;
          const float v = aM[mf][nf][j] + aC[mf][nf][j] * CSCL;
          // np: u3 = (h@u3w^T) + u3b, rounded once
          u3f[(size_t)(rb + mf * 16 + j) * 128 + gc] = v + u3b[gc];
        }
  }
}

// ================= u5gf: fused ew1 + u5 GEMM + ew2 epilogue
// Phase 0: stage u5wb -> ldsB (per-kt planes, staging swizzle).
// Phase 1: compute rh2 tile (ew1's exact op order) -> ldsA in the SAME
//          swizzled layout the staging would have produced (write slot =
//          data-slot ^ ((row>>1)&3), the verified involution).
// Phase 2: 3-product GEMM from LDS (no restaging), epilogue = r9 u5g.
__global__ __launch_bounds__(256, 1) void u5gf(const f16* __restrict__ u5wb,
                                               const float* __restrict__ pre,
                                               const float* __restrict__ u3f,
                                               const float* __restrict__ h,
                                               const float* __restrict__ w3b,
                                               const float* __restrict__ w4b,
                                               const float* __restrict__ w5b,
                                               const float* __restrict__ u5b,
                                               float* __restrict__ out) {
  __shared__ f16 ldsA[32768];  // rh2 tile: kt-planes {l0[128][32], l1'[128][32]}
  __shared__ f16 ldsB[32768];  // u5wb: same plane structure
  const int t = threadIdx.x;
  const int m0 = blockIdx.x * 128;
  const int wave = t >> 6;
  const int gs = (t & 3) ^ ((t >> 3) & 3);

  // ---- phase 0: issue B staging (16 gload16/thread; lands under phase 1)
#pragma unroll
  for (int kt = 0; kt < 4; ++kt)
#pragma unroll
    for (int lb = 0; lb < 2; ++lb)
#pragma unroll
      for (int g = 0; g < 2; ++g) {
        const int row_ = g * 64 + (t >> 2);
        gload16(u5wb + (size_t)row_ * 256 + lb * 128 + kt * 32 + gs * 8,
                ldsB + kt * 8192 + lb * 4096 + g * 2048 + wave * 512);
      }

  // ---- phase 1: rh2 tile. thread t: row r = t>>1, col-half ch = t&1.
  {
    const int r_ = t >> 1;
    const int ch = t & 1;
    const int gr_ = m0 + r_;
    const int bb_ = gr_ & 31, node_ = gr_ >> 5;
    const float* prow = pre + (size_t)gr_ * 384 + 128;
    const float* urow = u3f + (size_t)gr_ * 128;
    const float* hrow = h + ((size_t)bb_ * 1024 + node_) * 128;
    const int swk = (r_ >> 1) & 3;
#pragma unroll
    for (int s = 0; s < 8; ++s) {  // 8 slots x 8 cols
      const int c0 = ch * 64 + s * 8;
      const f32x4 p0 = *(const f32x4*)(prow + c0);
      const f32x4 p1 = *(const f32x4*)(prow + c0 + 4);
      const f32x4 u0 = *(const f32x4*)(urow + c0);
      const f32x4 u1 = *(const f32x4*)(urow + c0 + 4);
      const f32x4 h0 = *(const f32x4*)(hrow + c0);
      const f32x4 h1 = *(const f32x4*)(hrow + c0 + 4);
      const f32x4 b0 = *(const f32x4*)(w4b + c0);
      const f32x4 b1 = *(const f32x4*)(w4b + c0 + 4);
      f16 l0v[8], l1v[8];
#pragma unroll
      for (int j = 0; j < 4; ++j) {
        // ew1 op order: rr = sigmoid((p + w4b) + u3f); v = rr*h; split2
        const float ra = sigmoidf_((p0[j] + b0[j]) + u0[j]);
        split2(ra * h0[j], l0v[j], l1v[j]);
        const float rb2 = sigmoidf_((p1[j] + b1[j]) + u1[j]);
        split2(rb2 * h1[j], l0v[4 + j], l1v[4 + j]);
      }
      const int kt = c0 >> 5;
      const int sw = ((c0 >> 3) & 3) ^ swk;  // involution: data-slot ^ row-key
      *(f16x8*)&ldsA[kt * 8192 + r_ * 32 + sw * 8] = *(f16x8*)l0v;
      *(f16x8*)&ldsA[kt * 8192 + 4096 + r_ * 32 + sw * 8] = *(f16x8*)l1v;
    }
  }
  __syncthreads();  // drains vmcnt (B staged) + lgkmcnt (A written)

  // ---- phase 2: GEMM from LDS, product order identical to gemf
  f32x4 aM[4][4], aC[4][4];
  ACCZ4(aM);
  ACCZ4(aC);
  {
    const int lane = t & 63;
    const int wr = wave >> 1, wn = wave & 1;
    const int frow = lane & 15;
    const int fk = lane >> 4;
    const int sl = fk ^ ((frow >> 1) & 3);
    for (int kt = 0; kt < 4; ++kt) {
      const f16* ap = ldsA + kt * 8192;
      const f16* bp = ldsB + kt * 8192;
      f16x8 a0[4], a1[4], b0[4], b1[4];
#pragma unroll
      for (int nf = 0; nf < 4; ++nf) {
        const int row = wn * 64 + nf * 16 + frow;
        b0[nf] = *(const f16x8*)&bp[row * 32 + sl * 8];
        b1[nf] = *(const f16x8*)&bp[4096 + row * 32 + sl * 8];
      }
#pragma unroll
      for (int mf = 0; mf < 4; ++mf) {
        const int row = wr * 64 + mf * 16 + frow;
        a0[mf] = *(const f16x8*)&ap[row * 32 + sl * 8];
        a1[mf] = *(const f16x8*)&ap[4096 + row * 32 + sl * 8];
      }
      __builtin_amdgcn_s_setprio(1);
#pragma unroll
      for (int mf = 0; mf < 4; ++mf)
#pragma unroll
        for (int nf = 0; nf < 4; ++nf) {
          aC[mf][nf] = __builtin_amdgcn_mfma_f32_16x16x32_f16(a0[mf], b1[nf],
                                                              aC[mf][nf], 0, 0, 0);
          aC[mf][nf] = __builtin_amdgcn_mfma_f32_16x16x32_f16(a1[mf], b0[nf],
                                                              aC[mf][nf], 0, 0, 0);
        }
#pragma unroll
      for (int mf = 0; mf < 4; ++mf)
#pragma unroll
        for (int nf = 0; nf < 4; ++nf)
          aM[mf][nf] = __builtin_amdgcn_mfma_f32_16x16x32_f16(a0[mf], b0[nf],
                                                              aM[mf][nf], 0, 0, 0);
      __builtin_amdgcn_s_setprio(0);
    }
  }

  // ---- epilogue: identical to r9 u5g
  const int lane = t & 63;
  const int rb = m0 + (wave >> 1) * 64 + (lane >> 4) * 4;
  const int cb = (wave & 1) * 64 + (lane & 15);
#pragma unroll
  for (int mf = 0; mf < 4; ++mf)
#pragma unroll
    for (int nf = 0; nf < 4; ++nf)
#pragma unroll
      for (int j = 0; j < 4; ++j) {
        const int gr = rb + mf * 16 + j;
        const int gc = cb + nf * 16;
        const float v = aM[mf][nf][j] + aC[mf][nf][j] * CSCL;
        const float u5f = v + u5b[gc];  // np: U5 + u5b
        const float z = sigmoidf_((pre[(size_t)gr * 384 + gc] + w3b[gc]) +
                                  u3f[(size_t)gr * 128 + gc]);
        const float hv = tanhf((pre[(size_t)gr * 384 + 256 + gc] + w5b[gc]) + u5f);
        const int bb = gr & 31, node = gr >> 5;
        const size_t hi = ((size_t)bb * 1024 + node) * 128 + gc;
        const float hh = h[hi];
        out[hi] = (1.f - z) * hh + z * hv;  // np: (1-z)*h + z*hv
      }
}

// ================= pack h (fp32 [B][N][D]) -> hN2f 2-limb + X2 h-cols 2-limb
__global__ __launch_bounds__(256) void pack_h(const float* __restrict__ h,
                                              f16* __restrict__ hN2f,
                                              f16* __restrict__ X2) {
  __shared__ unsigned int lds01[128][33];
  const int t = threadIdx.x;
  const int b = blockIdx.y;
  const int n0 = blockIdx.x * 32;
#pragma unroll
  for (int i = 0; i < 16; ++i) {
    const int idx = i * 256 + t;
    const int nl = idx >> 7, d = idx & 127;
    const float v = h[((size_t)b * 1024 + n0 + nl) * 128 + d];
    f16 l0, l1;
    split2(v, l0, l1);
    const size_t xr = ((size_t)(n0 + nl) * 32 + b) * LDX + 256 + d;
    X2[xr] = l0;
    X2[xr + 384] = l1;
    lds01[d][nl] = (unsigned)bc16(l0) | ((unsigned)bc16(l1) << 16);
  }
  __syncthreads();
#pragma unroll
  for (int i = 0; i < 16; ++i) {
    const int idx = i * 256 + t;
    const int d = idx >> 5, nl = idx & 31;
    const unsigned pk = lds01[d][nl];
    f16* row = hN2f + (size_t)(b * 128 + d) * LDH + n0 + nl;
    row[0] = __builtin_bit_cast(f16, (unsigned short)(pk & 0xffffu));
    row[1024] = __builtin_bit_cast(f16, (unsigned short)(pk >> 16));
  }
}

// ================= init kernels
__global__ __launch_bounds__(256) void split_adjf(const float* __restrict__ src,
                                                  f16* __restrict__ dst) {
  const int i = blockIdx.x * 256 + threadIdx.x;  // 1M
  const int r = i >> 10, c = i & 1023;
  f16 l0, l1;
  split2(src[i], l0, l1);
  dst[(size_t)r * LDH + c] = l0;
  dst[(size_t)r * LDH + 1024 + c] = l1;
}

__global__ void build_wsm(const float* __restrict__ w3, const float* __restrict__ w4,
                          const float* __restrict__ w5, f16* __restrict__ Wsm) {
  const int k = blockIdx.x * 128 + threadIdx.x;  // 0..255
  const int j = blockIdx.y;                      // 0..383
  float v;
  if (j < 128) v = w3[j * 256 + k];
  else if (j < 256) v = w4[(j - 128) * 256 + k];
  else v = w5[(j - 256) * 256 + k];
  f16 l0, l1;
  split2(v, l0, l1);
  Wsm[(size_t)j * 512 + k] = l0;
  Wsm[(size_t)j * 512 + 256 + k] = l1;
}

__global__ void build_uw(const float* __restrict__ u, f16* __restrict__ dst) {
  const int i = blockIdx.x * 256 + threadIdx.x;  // 16384
  const int j = i >> 7, k = i & 127;
  f16 l0, l1;
  split2(u[i], l0, l1);
  dst[(size_t)j * 256 + k] = l0;
  dst[(size_t)j * 256 + 128 + k] = l1;
}

__global__ void sentinel(float* out, int n) {
  const int i = blockIdx.x * 256 + threadIdx.x;
  if (i < n) out[i] = 123456789.f;
}

extern "C" void kernel_launch(void* const* d_in, const int* in_sizes, int n_in,
                              void* d_out, int out_size, void* d_ws, size_t ws_size,
                              hipStream_t stream) {
  const float* input = (const float*)d_in[0];
  const float* Ain = (const float*)d_in[1];
  const float* Aout = (const float*)d_in[2];
  const float* w3w = (const float*)d_in[3];
  const float* w3b = (const float*)d_in[4];
  const float* u3w = (const float*)d_in[5];
  const float* u3b = (const float*)d_in[6];
  const float* w4w = (const float*)d_in[7];
  const float* w4b = (const float*)d_in[8];
  const float* w5w = (const float*)d_in[9];
  const float* w5b = (const float*)d_in[10];
  const float* u5wf = (const float*)d_in[11];
  const float* u5b = (const float*)d_in[12];
  // d_in[13] = time_step; fixed at 5 by the problem spec.

  char* ws = (char*)d_ws;
  size_t off = 0;
  auto alloc = [&](size_t bytes) -> void* {
    void* p = ws + off;
    off += (bytes + 255) & ~(size_t)255;
    return p;
  };
  f16* A2f = (f16*)alloc(2048ull * LDH * 2);   // 8.39 MB
  f16* hN2f = (f16*)alloc(4096ull * LDH * 2);  // 16.78 MB
  f16* X2 = (f16*)alloc(32768ull * LDX * 2);   // 50.33 MB
  f16* Wsm = (f16*)alloc(384ull * 512 * 2);
  f16* u3wb = (f16*)alloc(128ull * 256 * 2);
  f16* u5wb = (f16*)alloc(128ull * 256 * 2);
  float* pre = (float*)alloc(32768ull * 384 * 4);  // 50.33 MB
  float* u3f = (float*)alloc(32768ull * 128 * 4);  // 16.78 MB
  if (off > ws_size) {
    sentinel<<<dim3((out_size + 255) / 256), dim3(256), 0, stream>>>((float*)d_out, out_size);
    return;
  }

  split_adjf<<<dim3(4096), dim3(256), 0, stream>>>(Ain, A2f);
  split_adjf<<<dim3(4096), dim3(256), 0, stream>>>(Aout, A2f + 1024ull * LDH);
  build_wsm<<<dim3(2, 384), dim3(128), 0, stream>>>(w3w, w4w, w5w, Wsm);
  build_uw<<<dim3(64), dim3(256), 0, stream>>>(u3w, u3wb);
  build_uw<<<dim3(64), dim3(256), 0, stream>>>(u5wf, u5wb);

  float* out = (float*)d_out;
  const float* h = input;
  for (int step = 0; step < 5; ++step) {
    pack_h<<<dim3(32, 32), dim3(256), 0, stream>>>(h, hN2f, X2);
    adjf<<<dim3(32, 16), dim3(256), 0, stream>>>(A2f, hN2f, X2);
    densef<<<dim3(4, 256), dim3(256), 0, stream>>>(X2, Wsm, u3wb, u3b, pre, u3f);
    u5gf<<<dim3(256), dim3(256), 0, stream>>>(u5wb, pre, u3f, h, w3b, w4b, w5b, u5b,
                                              out);
    h = out;
  }
}